// Round 1
// 1127.356 us; speedup vs baseline: 1.2816x; 1.2816x over previous
//
#include <hip/hip_runtime.h>
#include <hip/hip_bf16.h>

typedef __attribute__((ext_vector_type(8))) short bf16x8;
typedef __attribute__((ext_vector_type(4))) float f32x4;

__device__ __forceinline__ void async16(const void* g, void* l) {
    __builtin_amdgcn_global_load_lds(
        (const __attribute__((address_space(1))) void*)g,
        (__attribute__((address_space(3))) void*)l,
        16, 0, 0);
}

__device__ __forceinline__ unsigned short f2bf(float f) {
    __hip_bfloat16 h = __float2bfloat16(f);
    union { __hip_bfloat16 h; unsigned short u; } cv;
    cv.h = h;
    return cv.u;
}

// 8 rows of x per block: V register block loaded once per K-chunk, reused
// across the 8 rows. Writes bf16 rows, computes h[row][0:8] = 2*codes*(x@V).
#define PREP_ROWS 8
__global__ __launch_bounds__(256) void prep_x(
    const float* __restrict__ x, const float* __restrict__ codes,
    const float* __restrict__ V, unsigned short* __restrict__ xb,
    float* __restrict__ h, int K) {
    const int row0 = blockIdx.x * PREP_ROWS;
    const int t = threadIdx.x;
    const int lane = t & 63, wave = t >> 6;

    float acc[PREP_ROWS][8];
    #pragma unroll
    for (int row = 0; row < PREP_ROWS; ++row)
        #pragma unroll
        for (int r = 0; r < 8; ++r) acc[row][r] = 0.f;

    // K=4096: 4 chunks, each thread owns 4 consecutive floats per chunk.
    for (int it = 0; it < 4; ++it) {
        const int d = (t + it * 256) * 4;
        // V[d..d+3][0:8] -> 32 registers (uncoalesced, but issued once per
        // 8 rows instead of once per row: 8x fewer line requests).
        const float* Vr = V + (size_t)d * 8;
        float vreg[4][8];
        #pragma unroll
        for (int q = 0; q < 4; ++q) {
            float4 a = ((const float4*)(Vr + q * 8))[0];
            float4 b = ((const float4*)(Vr + q * 8))[1];
            vreg[q][0] = a.x; vreg[q][1] = a.y; vreg[q][2] = a.z; vreg[q][3] = a.w;
            vreg[q][4] = b.x; vreg[q][5] = b.y; vreg[q][6] = b.z; vreg[q][7] = b.w;
        }
        #pragma unroll
        for (int row = 0; row < PREP_ROWS; ++row) {
            const size_t base = (size_t)(row0 + row) * K + d;
            float4 xv = *(const float4*)(x + base);
            ushort4 pk;
            pk.x = f2bf(xv.x); pk.y = f2bf(xv.y);
            pk.z = f2bf(xv.z); pk.w = f2bf(xv.w);
            *(ushort4*)(xb + base) = pk;
            float vx[4] = {xv.x, xv.y, xv.z, xv.w};
            #pragma unroll
            for (int q = 0; q < 4; ++q)
                #pragma unroll
                for (int r = 0; r < 8; ++r)
                    acc[row][r] += vx[q] * vreg[q][r];
        }
    }

    // wave reduce (64 lanes) per (row, r)
    #pragma unroll
    for (int row = 0; row < PREP_ROWS; ++row)
        #pragma unroll
        for (int r = 0; r < 8; ++r) {
            float a = acc[row][r];
            #pragma unroll
            for (int off = 32; off > 0; off >>= 1)
                a += __shfl_down(a, off);
            acc[row][r] = a;
        }

    __shared__ float red[4][PREP_ROWS][8];
    if (lane == 0)
        #pragma unroll
        for (int row = 0; row < PREP_ROWS; ++row)
            #pragma unroll
            for (int r = 0; r < 8; ++r) red[wave][row][r] = acc[row][r];
    __syncthreads();
    if (t < PREP_ROWS * 8) {
        const int row = t >> 3, r = t & 7;
        float s = red[0][row][r] + red[1][row][r] + red[2][row][r] + red[3][row][r];
        const size_t gi = (size_t)(row0 + row) * 8 + r;
        h[gi] = 2.0f * codes[gi] * s;
    }
}

__global__ __launch_bounds__(256) void cast_w(
    const float* __restrict__ W, unsigned short* __restrict__ Wb, long n4) {
    long i = (long)blockIdx.x * 256 + threadIdx.x;
    if (i < n4) {
        float4 w = ((const float4*)W)[i];
        ushort4 pk;
        pk.x = f2bf(w.x); pk.y = f2bf(w.y); pk.z = f2bf(w.z); pk.w = f2bf(w.w);
        ((ushort4*)Wb)[i] = pk;
    }
}

// C[m,n] = dot(A[m,:], B[n,:]) + bias[n] + dot8(h[m,:], U[n,:])
// A: [M,K] bf16 (x), B: [N,K] bf16 (W_base), out fp32.
// 128x128 block tile, BK=64, 4 waves each computing 64x64 via 4x4 MFMA 16x16x32.
__global__ __launch_bounds__(256, 2) void gemm_bt(
    const unsigned short* __restrict__ A, const unsigned short* __restrict__ B,
    const float* __restrict__ bias, const float* __restrict__ h,
    const float* __restrict__ U, float* __restrict__ C,
    int M, int N, int K) {
    __shared__ unsigned short As[128 * 64];
    __shared__ unsigned short Bs[128 * 64];

    const int t = threadIdx.x;
    const int lane = t & 63, wave = t >> 6;
    const int wm = wave >> 1, wn = wave & 1;
    const int quad = lane >> 4, l16 = lane & 15;
    const int m0 = blockIdx.y * 128, n0 = blockIdx.x * 128;

    f32x4 acc[4][4] = {};

    for (int k0 = 0; k0 < K; k0 += 64) {
        #pragma unroll
        for (int i = 0; i < 4; ++i) {
            int off = (t + i * 256) * 8;      // element offset in the 128x64 tile
            int r = off >> 6, c = off & 63;   // tile row / col
            async16(A + (size_t)(m0 + r) * K + k0 + c, &As[off]);
            async16(B + (size_t)(n0 + r) * K + k0 + c, &Bs[off]);
        }
        __syncthreads();
        #pragma unroll
        for (int kk = 0; kk < 64; kk += 32) {
            bf16x8 af[4], bfr[4];
            #pragma unroll
            for (int i = 0; i < 4; ++i)
                af[i] = *(const bf16x8*)&As[(wm * 64 + i * 16 + l16) * 64 + kk + quad * 8];
            #pragma unroll
            for (int j = 0; j < 4; ++j)
                bfr[j] = *(const bf16x8*)&Bs[(wn * 64 + j * 16 + l16) * 64 + kk + quad * 8];
            #pragma unroll
            for (int i = 0; i < 4; ++i)
                #pragma unroll
                for (int j = 0; j < 4; ++j)
                    acc[i][j] = __builtin_amdgcn_mfma_f32_16x16x32_bf16(
                        af[i], bfr[j], acc[i][j], 0, 0, 0);
        }
        __syncthreads();
    }

    // epilogue: bias + rank-8 lora dot, fp32 store
    float ufr[4][8];
    float bs[4];
    int gcol[4];
    #pragma unroll
    for (int j = 0; j < 4; ++j) {
        int col = n0 + wn * 64 + j * 16 + l16;
        gcol[j] = col;
        const float4* Ur = (const float4*)(U + (size_t)col * 8);
        float4 u0 = Ur[0], u1 = Ur[1];
        ufr[j][0] = u0.x; ufr[j][1] = u0.y; ufr[j][2] = u0.z; ufr[j][3] = u0.w;
        ufr[j][4] = u1.x; ufr[j][5] = u1.y; ufr[j][6] = u1.z; ufr[j][7] = u1.w;
        bs[j] = bias[col];
    }
    #pragma unroll
    for (int i = 0; i < 4; ++i) {
        #pragma unroll
        for (int r = 0; r < 4; ++r) {
            int grow = m0 + wm * 64 + i * 16 + quad * 4 + r;
            const float4* hr = (const float4*)(h + (size_t)grow * 8);
            float4 h0 = hr[0], h1 = hr[1];
            float hv[8] = {h0.x, h0.y, h0.z, h0.w, h1.x, h1.y, h1.z, h1.w};
            #pragma unroll
            for (int j = 0; j < 4; ++j) {
                float v = acc[i][j][r] + bs[j];
                #pragma unroll
                for (int q = 0; q < 8; ++q) v += hv[q] * ufr[j][q];
                C[(size_t)grow * N + gcol[j]] = v;
            }
        }
    }
}

extern "C" void kernel_launch(void* const* d_in, const int* in_sizes, int n_in,
                              void* d_out, int out_size, void* d_ws, size_t ws_size,
                              hipStream_t stream) {
    const float* x     = (const float*)d_in[0];
    const float* codes = (const float*)d_in[1];
    const float* W     = (const float*)d_in[2];
    const float* b     = (const float*)d_in[3];
    const float* V     = (const float*)d_in[4];
    const float* U     = (const float*)d_in[5];
    float* out = (float*)d_out;

    const int N = in_sizes[3];                 // D_OUT = 4096
    const int K = in_sizes[2] / N;             // D_IN  = 4096
    const int M = in_sizes[0] / K;             // B*S   = 16384

    char* ws = (char*)d_ws;
    unsigned short* xb = (unsigned short*)ws;                       // M*K bf16
    unsigned short* Wb = (unsigned short*)(ws + (size_t)M * K * 2); // N*K bf16
    float* h = (float*)(ws + (size_t)M * K * 2 + (size_t)N * K * 2);// M*8 fp32

    prep_x<<<M / PREP_ROWS, 256, 0, stream>>>(x, codes, V, xb, h, K);
    long n4 = (long)N * K / 4;
    cast_w<<<(int)((n4 + 255) / 256), 256, 0, stream>>>(W, Wb, n4);
    dim3 grid(N / 128, M / 128);
    gemm_bt<<<grid, 256, 0, stream>>>(xb, Wb, b, h, U, out, M, N, K);
}